// Round 2
// baseline (870.191 us; speedup 1.0000x reference)
//
#include <hip/hip_runtime.h>
#include <hip/hip_bf16.h>

// Problem constants (from reference)
#define BATCH 2048
#define POOL 32
#define SEL 16
#define PLEN 8
#define DIM 768
#define DIM4 (DIM / 4)          // 192 float4 per row
#define ROW4 (PLEN * DIM4)      // 1536 float4 per prompt
#define TILE4 (SEL * ROW4)      // 24576 float4 of selection per batch row
#define SIM_N (BATCH * SEL)     // 32768

typedef float f32x4 __attribute__((ext_vector_type(4)));

// ---------------------------------------------------------------------------
// Kernel A: match[b][p] = cos-sim(query[b], key[p]), split-K by 4.
// 1024 blocks x 256 threads: block covers 2 query rows; thread = (b, p, s),
// s in [0,4) owns 48 of the 192 float4 pairs. LDS-reduce over s, then the
// s==0 lanes (p = 0..31 within a wave) compute rank via width-32 shuffles
// (exact jax top_k tie-break: value desc, index asc) and vote counts.
// ---------------------------------------------------------------------------
__global__ __launch_bounds__(256) void match_count_kernel(
    const float* __restrict__ q, const float* __restrict__ pk,
    float* __restrict__ match, int* __restrict__ counts) {
    int t = threadIdx.x;
    int b_local = t >> 7;                 // 0..1
    int within  = t & 127;
    int p = within & 31;
    int s = within >> 5;                  // 0..3
    int b = blockIdx.x * 2 + b_local;

    const f32x4* q4 = (const f32x4*)q + (size_t)b * DIM4 + s * 48;
    const f32x4* k4 = (const f32x4*)pk + (size_t)p * DIM4 + s * 48;
    float dot = 0.f, qq = 0.f, kk = 0.f;
#pragma unroll 6
    for (int i = 0; i < 48; ++i) {
        f32x4 a = q4[i];
        f32x4 c = k4[i];
        dot += a.x * c.x + a.y * c.y + a.z * c.z + a.w * c.w;
        qq  += a.x * a.x + a.y * a.y + a.z * a.z + a.w * a.w;
        kk  += c.x * c.x + c.y * c.y + c.z * c.z + c.w * c.w;
    }

    __shared__ float rdot[256], rqq[256], rkk[256];
    __shared__ int cnt[POOL];
    rdot[t] = dot; rqq[t] = qq; rkk[t] = kk;
    if (t < POOL) cnt[t] = 0;
    __syncthreads();

    if (s == 0) {
        int base = t;                     // = b_local*128 + p
        dot = rdot[base] + rdot[base + 32] + rdot[base + 64] + rdot[base + 96];
        qq  = rqq[base]  + rqq[base + 32]  + rqq[base + 64]  + rqq[base + 96];
        kk  = rkk[base]  + rkk[base + 32]  + rkk[base + 64]  + rkk[base + 96];
        float m = dot / fmaxf(sqrtf(qq) * sqrtf(kk), 1e-8f);
        match[b * POOL + p] = m;
        // rank within row: #(v_j > v) with ties broken by lower index
        int rank = 0;
        for (int i = 0; i < POOL; ++i) {
            float vm = __shfl(m, i, 32);  // lanes 0..31 of this wave hold the row
            rank += (vm > m || (vm == m && i < p)) ? 1 : 0;
        }
        if (rank < SEL) atomicAdd(&cnt[p], 1);
    }
    __syncthreads();
    if (t < POOL) atomicAdd(&counts[t], cnt[t]);
}

// ---------------------------------------------------------------------------
// Kernel B: single thread. mosts = top-16 of counts (count desc, index asc —
// jax.lax.top_k tie semantics). nonk = complement indices, ascending.
// ---------------------------------------------------------------------------
__global__ void select_kernel(const int* __restrict__ counts,
                              int* __restrict__ mosts, int* __restrict__ nonk) {
    if (threadIdx.x == 0 && blockIdx.x == 0) {
        int c[POOL];
        for (int i = 0; i < POOL; ++i) c[i] = counts[i];
        int selrank[POOL];
        for (int i = 0; i < POOL; ++i) {
            int r = 0;
            for (int j = 0; j < POOL; ++j)
                r += (c[j] > c[i] || (c[j] == c[i] && j < i)) ? 1 : 0;
            selrank[i] = r;
            if (r < SEL) mosts[r] = i;
        }
        int np = 0;
        for (int i = 0; i < POOL; ++i)
            if (selrank[i] >= SEL) nonk[np++] = i;
    }
}

// ---------------------------------------------------------------------------
// Kernel C: sim[b][j] = match[b][mosts[j]]; unsim[b][j] = match[b][nonk[j]]
// ---------------------------------------------------------------------------
__global__ __launch_bounds__(256) void simuns_kernel(
    const float* __restrict__ match, const int* __restrict__ mosts,
    const int* __restrict__ nonk, float* __restrict__ out) {
    __shared__ int sm[SEL], sn[SEL];
    if (threadIdx.x < SEL) sm[threadIdx.x] = mosts[threadIdx.x];
    else if (threadIdx.x < 2 * SEL) sn[threadIdx.x - SEL] = nonk[threadIdx.x - SEL];
    __syncthreads();
    int tid = blockIdx.x * 256 + threadIdx.x;   // 65536 threads
    int b = tid >> 5;
    int j = tid & 31;
    if (j < SEL)
        out[b * SEL + j] = match[b * POOL + sm[j]];
    else
        out[SIM_N + b * SEL + (j - SEL)] = match[b * POOL + sn[j - SEL]];
}

// ---------------------------------------------------------------------------
// Kernel D: the 805 MB broadcast write. One block per batch row: 96 float4
// per thread, jj/kk nesting eliminates the /1536, reads are L2-resident
// (prompts = 786 KB), writes are nontemporal (write-once, never re-read on
// device — keep them out of L2).
// ---------------------------------------------------------------------------
__global__ __launch_bounds__(256) void sel_write_kernel(
    const f32x4* __restrict__ prompts4, const int* __restrict__ mosts,
    f32x4* __restrict__ out4) {
    __shared__ int sm[SEL];
    if (threadIdx.x < SEL) sm[threadIdx.x] = mosts[threadIdx.x];
    __syncthreads();
    int t = threadIdx.x;
    f32x4* dst = out4 + (size_t)blockIdx.x * TILE4;
#pragma unroll 2
    for (int jj = 0; jj < SEL; ++jj) {
        const f32x4* src = prompts4 + (size_t)sm[jj] * ROW4;
        f32x4* d = dst + jj * ROW4;
#pragma unroll
        for (int kk = 0; kk < 6; ++kk) {          // 6*256 = 1536 = ROW4
            f32x4 v = src[kk * 256 + t];
            __builtin_nontemporal_store(v, d + kk * 256 + t);
        }
    }
}

// ---------------------------------------------------------------------------
extern "C" void kernel_launch(void* const* d_in, const int* in_sizes, int n_in,
                              void* d_out, int out_size, void* d_ws, size_t ws_size,
                              hipStream_t stream) {
    const float* query   = (const float*)d_in[0];   // [2048, 768]
    const float* pkey    = (const float*)d_in[1];   // [32, 768]
    const float* prompts = (const float*)d_in[2];   // [32, 8, 768]
    float* out = (float*)d_out;

    // workspace layout
    float* match = (float*)d_ws;                          // 65536 f32 = 256 KiB
    int* counts  = (int*)((char*)d_ws + 65536 * 4);       // 32 i32
    int* mosts   = counts + POOL;                         // 16 i32
    int* nonk    = mosts + SEL;                           // 16 i32

    hipMemsetAsync(counts, 0, POOL * sizeof(int), stream);

    match_count_kernel<<<BATCH / 2, 256, 0, stream>>>(query, pkey, match, counts);
    select_kernel<<<1, 64, 0, stream>>>(counts, mosts, nonk);
    simuns_kernel<<<(BATCH * POOL) / 256, 256, 0, stream>>>(match, mosts, nonk, out);

    f32x4* sel_out = (f32x4*)(out + 2 * SIM_N);   // selection starts at float 65536
    sel_write_kernel<<<BATCH, 256, 0, stream>>>(
        (const f32x4*)prompts, mosts, sel_out);
}